// Round 12
// baseline (623.972 us; speedup 1.0000x reference)
//
#include <hip/hip_runtime.h>
#include <math.h>

#define N_NODES 100000
#define K_NBRS 16
#define N_EDGES (N_NODES * K_NBRS)
#define TPB 256
#define NBLK 2048
#define QTAB ((size_t)N_NODES * 16)   // one channel-quarter table (ushorts)

typedef __attribute__((ext_vector_type(8))) short short8;   // bf16x8 MFMA frag
typedef __attribute__((ext_vector_type(4))) float float4_;  // MFMA C/D frag
typedef __attribute__((ext_vector_type(4))) int int4_;

// RNE float->bf16 (bits) and back
__device__ __forceinline__ unsigned short f2bf(float f) {
  unsigned int u = __float_as_uint(f);
  u += 0x7fffu + ((u >> 16) & 1u);
  return (unsigned short)(u >> 16);
}
__device__ __forceinline__ float bf2f(unsigned short b) {
  return __uint_as_float(((unsigned int)b) << 16);
}
__device__ __forceinline__ float lo2f(unsigned int v) {  // low bf16 of packed pair
  return __uint_as_float(v << 16);
}
__device__ __forceinline__ float hi2f(unsigned int v) {  // high bf16 of packed pair
  return __uint_as_float(v & 0xffff0000u);
}

// Merged: (1) normalize edge_index row0 to int32; (2) layer-1 node GEMM.
// A/B written in channel-QUARTERED layout: table cq holds [N][16] ushort
// (3.2MB < 4MB per-XCD L2 -> gather working set becomes L2-resident).
__global__ void k_pre(const int* __restrict__ ei, int* __restrict__ srcout,
                      const float* __restrict__ x, const float* __restrict__ W1,
                      const float* __restrict__ b1,
                      unsigned short* __restrict__ A, unsigned short* __restrict__ B) {
  const bool is64 = (ei[1] == 0) && (ei[3] == 0) && (ei[5] == 0) && (ei[7] == 0);
  const int tid = blockIdx.x * blockDim.x + threadIdx.x;
  const int stride = gridDim.x * blockDim.x;
  for (int e = tid; e < N_EDGES; e += stride)
    srcout[e] = is64 ? ei[2 * e] : ei[e];

  const int lane = threadIdx.x & 63;
  const int cq = lane >> 4, lc = lane & 15;
  const int nwaves = stride >> 6;
  const int wid0 = tid >> 6;
  float w[6];
#pragma unroll
  for (int k = 0; k < 6; ++k) w[k] = W1[k * 64 + lane];
  const float bias = b1[lane];
  for (int i0 = wid0; i0 < N_NODES; i0 += nwaves) {
    const int i = __builtin_amdgcn_readfirstlane(i0);
    const float x0 = x[3 * i], x1 = x[3 * i + 1], x2 = x[3 * i + 2];
    const float b = fmaf(x0, w[3], fmaf(x1, w[4], x2 * w[5]));
    const float a = bias + fmaf(x0, w[0] - w[3],
                          fmaf(x1, w[1] - w[4], x2 * (w[2] - w[5])));
    A[cq * QTAB + (size_t)i * 16 + lc] = f2bf(a);
    B[cq * QTAB + (size_t)i * 16 + lc] = f2bf(b);
  }
}

// Aggregation v6: 4 channel-quarter passes; per pass the gather table is
// 3.2MB -> fits every XCD's 4MB L2 -> gathers are L2 hits (was ~2/3 L3
// misses on the 12.8MB table = the ~45us floor). 8-lane group per node,
// 2 channels/lane (packed uint). Grid 2048x4waves = exactly resident.
template <bool DO_GMAX>
__global__ void k_aggr(const int* __restrict__ src,
                       const unsigned short* __restrict__ Aq,
                       const unsigned short* __restrict__ Bq,
                       unsigned short* __restrict__ hout, float* __restrict__ P) {
  const int lane = threadIdx.x & 63;
  const int g8 = lane >> 3;        // group owns node i0+g8
  const int l8 = lane & 7;         // channels 2*l8, 2*l8+1 within quarter
  const int nw = (gridDim.x * blockDim.x) >> 6;
  const int w0 = (blockIdx.x * blockDim.x + threadIdx.x) >> 6;
  float gmax[4][2];
#pragma unroll
  for (int c = 0; c < 4; ++c) gmax[c][0] = gmax[c][1] = 0.f;
#pragma unroll 1
  for (int cq = 0; cq < 4; ++cq) {
    const unsigned short* At = Aq + cq * QTAB;
    const unsigned short* Bt = Bq + cq * QTAB;
    for (int p = w0; p * 8 < N_NODES; p += nw) {
      const int i = __builtin_amdgcn_readfirstlane(p * 8) + g8;
      const int* sp = src + (size_t)i * K_NBRS;   // uniform within group
      int4_ idx[4];
#pragma unroll
      for (int e4 = 0; e4 < 4; ++e4)
        idx[e4] = *(const int4_*)(sp + e4 * 4);
      unsigned int gv[16];
#pragma unroll
      for (int e4 = 0; e4 < 4; ++e4)
#pragma unroll
        for (int e = 0; e < 4; ++e)
          gv[e4 * 4 + e] =
              *(const unsigned int*)(Bt + (size_t)idx[e4][e] * 16 + l8 * 2);
      const unsigned int av =
          *(const unsigned int*)(At + (size_t)i * 16 + l8 * 2);
      // 15-fmax tree per channel (same order as v5 -> identical numerics)
      float m0 = fmaxf(fmaxf(fmaxf(fmaxf(lo2f(gv[0]), lo2f(gv[1])),
                                   fmaxf(lo2f(gv[2]), lo2f(gv[3]))),
                             fmaxf(fmaxf(lo2f(gv[4]), lo2f(gv[5])),
                                   fmaxf(lo2f(gv[6]), lo2f(gv[7])))),
                       fmaxf(fmaxf(fmaxf(lo2f(gv[8]), lo2f(gv[9])),
                                   fmaxf(lo2f(gv[10]), lo2f(gv[11]))),
                             fmaxf(fmaxf(lo2f(gv[12]), lo2f(gv[13])),
                                   fmaxf(lo2f(gv[14]), lo2f(gv[15])))));
      float m1 = fmaxf(fmaxf(fmaxf(fmaxf(hi2f(gv[0]), hi2f(gv[1])),
                                   fmaxf(hi2f(gv[2]), hi2f(gv[3]))),
                             fmaxf(fmaxf(hi2f(gv[4]), hi2f(gv[5])),
                                   fmaxf(hi2f(gv[6]), hi2f(gv[7])))),
                       fmaxf(fmaxf(fmaxf(hi2f(gv[8]), hi2f(gv[9])),
                                   fmaxf(hi2f(gv[10]), hi2f(gv[11]))),
                             fmaxf(fmaxf(hi2f(gv[12]), hi2f(gv[13])),
                                   fmaxf(hi2f(gv[14]), hi2f(gv[15])))));
      const float h0 = fmaxf(lo2f(av) + m0, 0.f);
      const float h1 = fmaxf(hi2f(av) + m1, 0.f);
      const unsigned int hp =
          (unsigned int)f2bf(h0) | ((unsigned int)f2bf(h1) << 16);
      *(unsigned int*)(hout + (size_t)i * 64 + cq * 16 + l8 * 2) = hp;
      if constexpr (DO_GMAX) {
        gmax[cq][0] = fmaxf(gmax[cq][0], h0);
        gmax[cq][1] = fmaxf(gmax[cq][1], h1);
      }
    }
  }
  if constexpr (DO_GMAX) {
    __shared__ float red[TPB][8];
#pragma unroll
    for (int c = 0; c < 4; ++c) {
      red[threadIdx.x][c * 2] = gmax[c][0];
      red[threadIdx.x][c * 2 + 1] = gmax[c][1];
    }
    __syncthreads();
    if (threadIdx.x < 64) {
      const int c = threadIdx.x;
      const int cq = c >> 4, rem = c & 15, l8r = rem >> 1, t = rem & 1;
      float mm = 0.f;
#pragma unroll
      for (int w = 0; w < 4; ++w)
#pragma unroll
        for (int g = 0; g < 8; ++g)
          mm = fmaxf(mm, red[w * 64 + g * 8 + l8r][cq * 2 + t]);
      P[(size_t)blockIdx.x * 64 + c] = mm;
    }
  }
}

// MFMA node-GEMM: [Aout|Bout] = h @ [Wtop-Wbot | Wbot] (+bias on A).
// Reads h [node][64]; writes A/B in QUARTERED layout.
__global__ __launch_bounds__(TPB, 2)
void k_gemm(const unsigned short* __restrict__ h, const float* __restrict__ W,
            const float* __restrict__ bn,
            unsigned short* __restrict__ Aout, unsigned short* __restrict__ Bout) {
  __shared__ __align__(16) unsigned short lwhi[128 * 72];  // W'^T [j][k]
  __shared__ __align__(16) unsigned short lwlo[128 * 72];
  for (int idx = threadIdx.x; idx < 8192; idx += TPB) {
    const int k = idx >> 7, j = idx & 127;
    const float v = (j < 64) ? (W[k * 64 + j] - W[(64 + k) * 64 + j])
                             : W[(64 + k) * 64 + (j - 64)];
    const unsigned short hi = f2bf(v);
    lwhi[j * 72 + k] = hi;
    lwlo[j * 72 + k] = f2bf(v - bf2f(hi));
  }
  __syncthreads();
  const int lane = threadIdx.x & 63;
  const int wav = threadIdx.x >> 6;
  const int l15 = lane & 15, lg = lane >> 4;
  short8 bhi[8][2], blo[8][2];
#pragma unroll
  for (int ct = 0; ct < 8; ++ct)
#pragma unroll
    for (int kk = 0; kk < 2; ++kk) {
      const int off = (ct * 16 + l15) * 72 + kk * 32 + lg * 8;
      bhi[ct][kk] = *(const short8*)&lwhi[off];
      blo[ct][kk] = *(const short8*)&lwlo[off];
    }
  float bv[4];
#pragma unroll
  for (int ct = 0; ct < 4; ++ct) bv[ct] = bn[ct * 16 + l15];
  const int NT = (N_NODES + 63) / 64;
  for (int t = blockIdx.x; t < NT; t += gridDim.x) {
    const int nb = t * 64 + wav * 16;
    const int row = min(nb + l15, N_NODES - 1);
    const unsigned short* hr = h + (size_t)row * 64;
    float4_ acc[8];
#pragma unroll
    for (int ct = 0; ct < 8; ++ct) acc[ct] = (float4_)(0.f);
#pragma unroll
    for (int kk = 0; kk < 2; ++kk) {
      const short8 ahi = *(const short8*)(hr + kk * 32 + lg * 8);
#pragma unroll
      for (int ct = 0; ct < 8; ++ct) {
        acc[ct] = __builtin_amdgcn_mfma_f32_16x16x32_bf16(ahi, bhi[ct][kk], acc[ct], 0, 0, 0);
        acc[ct] = __builtin_amdgcn_mfma_f32_16x16x32_bf16(ahi, blo[ct][kk], acc[ct], 0, 0, 0);
      }
    }
#pragma unroll
    for (int ct = 0; ct < 8; ++ct)
#pragma unroll
      for (int r = 0; r < 4; ++r) {
        const int node = nb + lg * 4 + r;
        if (node < N_NODES) {
          if (ct < 4)
            Aout[ct * QTAB + (size_t)node * 16 + l15] = f2bf(acc[ct][r] + bv[ct]);
          else
            Bout[(ct - 4) * QTAB + (size_t)node * 16 + l15] = f2bf(acc[ct][r]);
        }
      }
  }
}

// Tree-reduce 2048 per-block partials to g[64].
__global__ void k_gred(const float* __restrict__ P, float* __restrict__ g) {
  __shared__ float red[16][64];
  const int lane = threadIdx.x & 63;
  const int w = threadIdx.x >> 6;
  float m = 0.f;
  for (int r = w; r < NBLK; r += 16)
    m = fmaxf(m, P[(size_t)r * 64 + lane]);
  red[w][lane] = m;
  __syncthreads();
  if (threadIdx.x < 64) {
    float mm = 0.f;
#pragma unroll
    for (int k = 0; k < 16; ++k) mm = fmaxf(mm, red[k][lane]);
    g[lane] = mm;
  }
}

// Head: hidden = relu(h @ Wa_top + gt), gt = ba + g @ Wa_bot;
// out = x + hidden @ Wb + bb.
__global__ __launch_bounds__(TPB, 2)
void k_final(const unsigned short* __restrict__ h, const float* __restrict__ g,
             const float* __restrict__ Wa, const float* __restrict__ ba,
             const float* __restrict__ Wb, const float* __restrict__ bb,
             const float* __restrict__ x, float* __restrict__ out) {
  __shared__ __align__(16) unsigned short lwhi[128 * 72];
  __shared__ __align__(16) unsigned short lwlo[128 * 72];
  __shared__ float sgt[128];
  for (int idx = threadIdx.x; idx < 8192; idx += TPB) {
    const int k = idx >> 7, j = idx & 127;
    const float v = Wa[k * 128 + j];
    const unsigned short hi = f2bf(v);
    lwhi[j * 72 + k] = hi;
    lwlo[j * 72 + k] = f2bf(v - bf2f(hi));
  }
  if (threadIdx.x < 128) {
    const int c = threadIdx.x;
    float s = ba[c];
    for (int k = 0; k < 64; ++k) s = fmaf(g[k], Wa[(64 + k) * 128 + c], s);
    sgt[c] = s;
  }
  __syncthreads();
  const int lane = threadIdx.x & 63;
  const int wav = threadIdx.x >> 6;
  const int l15 = lane & 15, lg = lane >> 4;
  short8 bhi[8][2], blo[8][2];
#pragma unroll
  for (int ct = 0; ct < 8; ++ct)
#pragma unroll
    for (int kk = 0; kk < 2; ++kk) {
      const int off = (ct * 16 + l15) * 72 + kk * 32 + lg * 8;
      bhi[ct][kk] = *(const short8*)&lwhi[off];
      blo[ct][kk] = *(const short8*)&lwlo[off];
    }
  float gtv[8];
#pragma unroll
  for (int ct = 0; ct < 8; ++ct) gtv[ct] = sgt[ct * 16 + l15];
  float wbv[8][3];
#pragma unroll
  for (int ct = 0; ct < 8; ++ct)
#pragma unroll
    for (int jj = 0; jj < 3; ++jj)
      wbv[ct][jj] = Wb[(ct * 16 + l15) * 3 + jj];
  const float bbl = (l15 == 0) ? bb[0] : (l15 == 1 ? bb[1] : bb[2]);
  const int NT = (N_NODES + 63) / 64;
  for (int t = blockIdx.x; t < NT; t += gridDim.x) {
    const int nb = t * 64 + wav * 16;
    const int row = min(nb + l15, N_NODES - 1);
    const unsigned short* hr = h + (size_t)row * 64;
    float4_ acc[8];
#pragma unroll
    for (int ct = 0; ct < 8; ++ct) acc[ct] = (float4_)(0.f);
#pragma unroll
    for (int kk = 0; kk < 2; ++kk) {
      const short8 ahi = *(const short8*)(hr + kk * 32 + lg * 8);
#pragma unroll
      for (int ct = 0; ct < 8; ++ct) {
        acc[ct] = __builtin_amdgcn_mfma_f32_16x16x32_bf16(ahi, bhi[ct][kk], acc[ct], 0, 0, 0);
        acc[ct] = __builtin_amdgcn_mfma_f32_16x16x32_bf16(ahi, blo[ct][kk], acc[ct], 0, 0, 0);
      }
    }
#pragma unroll
    for (int r = 0; r < 4; ++r) {
      float t0 = 0.f, t1 = 0.f, t2 = 0.f;
#pragma unroll
      for (int ct = 0; ct < 8; ++ct) {
        const float hd = fmaxf(acc[ct][r] + gtv[ct], 0.f);
        t0 = fmaf(hd, wbv[ct][0], t0);
        t1 = fmaf(hd, wbv[ct][1], t1);
        t2 = fmaf(hd, wbv[ct][2], t2);
      }
#pragma unroll
      for (int off = 1; off < 16; off <<= 1) {
        t0 += __shfl_xor(t0, off);
        t1 += __shfl_xor(t1, off);
        t2 += __shfl_xor(t2, off);
      }
      const int node = nb + lg * 4 + r;
      if (node < N_NODES && l15 < 3) {
        const float tj = (l15 == 0) ? t0 : (l15 == 1 ? t1 : t2);
        out[(size_t)node * 3 + l15] = x[(size_t)node * 3 + l15] + tj + bbl;
      }
    }
  }
}

extern "C" void kernel_launch(void* const* d_in, const int* in_sizes, int n_in,
                              void* d_out, int out_size, void* d_ws, size_t ws_size,
                              hipStream_t stream) {
  const float* x  = (const float*)d_in[0];
  const int*   ei = (const int*)d_in[1];
  const float* W1 = (const float*)d_in[2];
  const float* b1 = (const float*)d_in[3];
  const float* W2 = (const float*)d_in[4];
  const float* b2 = (const float*)d_in[5];
  const float* W3 = (const float*)d_in[6];
  const float* b3 = (const float*)d_in[7];
  const float* W4 = (const float*)d_in[8];
  const float* b4 = (const float*)d_in[9];
  const float* W5 = (const float*)d_in[10];
  const float* b5 = (const float*)d_in[11];
  const float* Wa = (const float*)d_in[12];
  const float* ba = (const float*)d_in[13];
  const float* Wb = (const float*)d_in[14];
  const float* bb = (const float*)d_in[15];
  float* out = (float*)d_out;

  // ws layout: src[1.6M int] | A0,B0,A1,B1 (quartered),H [6.4M ushort each] | P | g
  float* ws = (float*)d_ws;
  int* srcbuf = (int*)ws;
  unsigned short* A0 = (unsigned short*)(ws + 1600000);
  unsigned short* B0 = A0 + 6400000;
  unsigned short* A1 = B0 + 6400000;
  unsigned short* B1 = A1 + 6400000;
  unsigned short* H  = B1 + 6400000;
  float* P = (float*)(H + 6400000);
  float* g = P + (size_t)NBLK * 64;

  k_pre<<<NBLK, TPB, 0, stream>>>(ei, srcbuf, x, W1, b1, A0, B0);
  k_aggr<false><<<NBLK, TPB, 0, stream>>>(srcbuf, A0, B0, H, nullptr);
  k_gemm<<<1024, TPB, 0, stream>>>(H, W2, b2, A1, B1);
  k_aggr<false><<<NBLK, TPB, 0, stream>>>(srcbuf, A1, B1, H, nullptr);
  k_gemm<<<1024, TPB, 0, stream>>>(H, W3, b3, A0, B0);
  k_aggr<false><<<NBLK, TPB, 0, stream>>>(srcbuf, A0, B0, H, nullptr);
  k_gemm<<<1024, TPB, 0, stream>>>(H, W4, b4, A1, B1);
  k_aggr<false><<<NBLK, TPB, 0, stream>>>(srcbuf, A1, B1, H, nullptr);
  k_gemm<<<1024, TPB, 0, stream>>>(H, W5, b5, A0, B0);
  k_aggr<true><<<NBLK, TPB, 0, stream>>>(srcbuf, A0, B0, H, P);
  k_gred<<<1, 1024, 0, stream>>>(P, g);
  k_final<<<512, TPB, 0, stream>>>(H, g, Wa, ba, Wb, bb, x, out);
}